// Round 1
// baseline (1084.916 us; speedup 1.0000x reference)
//
#include <hip/hip_runtime.h>

typedef short short8 __attribute__((ext_vector_type(8)));
typedef float f32x4 __attribute__((ext_vector_type(4)));
typedef int int4v __attribute__((ext_vector_type(4)));

#define B_ 2
#define S_ 2048
#define D_ 2048
#define H_ 16
#define HD_ 128

__device__ inline ushort f2bf(float f) {
    union { float f; unsigned u; } v; v.f = f;
    unsigned r = v.u + 0x7FFFu + ((v.u >> 16) & 1u);
    return (ushort)(r >> 16);
}
__device__ inline float bf2f(ushort b) {
    union { unsigned u; float f; } v; v.u = ((unsigned)b) << 16;
    return v.f;
}

// fp32 -> bf16 cast, 4 elems/thread
__global__ void cast_kernel(const float* __restrict__ src, ushort* __restrict__ dst, int n4) {
    int i = blockIdx.x * blockDim.x + threadIdx.x;
    if (i >= n4) return;
    float4 v = reinterpret_cast<const float4*>(src)[i];
    ushort4 o;
    o.x = f2bf(v.x); o.y = f2bf(v.y); o.z = f2bf(v.z); o.w = f2bf(v.w);
    reinterpret_cast<ushort4*>(dst)[i] = o;
}

// in-place RoPE on (B,S,H,HD) bf16, one (even,odd) pair per thread
__global__ void rope_kernel(ushort* __restrict__ t, const float* __restrict__ cosT,
                            const float* __restrict__ sinT, int npairs) {
    int pid = blockIdx.x * blockDim.x + threadIdx.x;
    if (pid >= npairs) return;
    int i = pid & 63;
    int s = (pid >> 10) & (S_ - 1);
    unsigned pr = reinterpret_cast<unsigned*>(t)[pid];
    float e = bf2f((ushort)(pr & 0xFFFFu));
    float o = bf2f((ushort)(pr >> 16));
    float c = cosT[s * 64 + i];
    float sn = sinT[s * 64 + i];
    float oe = e * c - o * sn;
    float oo = e * sn + o * c;
    unsigned outp = ((unsigned)f2bf(oo) << 16) | (unsigned)f2bf(oe);
    reinterpret_cast<unsigned*>(t)[pid] = outp;
}

// C[M][N] = A[M][K] @ B[K][N], bf16 in, fp32 acc; 64x64 tile, 4 waves, BK=32
template<bool F32OUT>
__global__ __launch_bounds__(256) void gemm_kernel(const ushort* __restrict__ A,
        const ushort* __restrict__ Bm, void* __restrict__ Cout, int M, int N, int K) {
    __shared__ ushort As[64][40];   // [m][k], padded (stride 80B: 2-way max)
    __shared__ ushort Bs[64][40];   // [n][k] transposed
    const int tid = threadIdx.x;
    const int lane = tid & 63;
    const int wv = tid >> 6;
    const int wm = wv >> 1, wn = wv & 1;
    const int bm = blockIdx.y * 64, bn = blockIdx.x * 64;
    const int l15 = lane & 15, lg = lane >> 4;

    f32x4 acc[2][2] = {};
    const int arow = tid >> 2, ac8 = (tid & 3) * 8;
    const int brow = tid >> 3, bc8 = (tid & 7) * 8;

    for (int k0 = 0; k0 < K; k0 += 32) {
        __syncthreads();
        int4v av = *reinterpret_cast<const int4v*>(&A[(size_t)(bm + arow) * K + k0 + ac8]);
        *reinterpret_cast<int4v*>(&As[arow][ac8]) = av;
        int4v bvv = *reinterpret_cast<const int4v*>(&Bm[(size_t)(k0 + brow) * N + bn + bc8]);
        const ushort* bvp = reinterpret_cast<const ushort*>(&bvv);
        #pragma unroll
        for (int j = 0; j < 8; ++j) Bs[bc8 + j][brow] = bvp[j];
        __syncthreads();
        short8 a0 = *reinterpret_cast<const short8*>(&As[wm * 32 + l15][lg * 8]);
        short8 a1 = *reinterpret_cast<const short8*>(&As[wm * 32 + 16 + l15][lg * 8]);
        short8 b0 = *reinterpret_cast<const short8*>(&Bs[wn * 32 + l15][lg * 8]);
        short8 b1 = *reinterpret_cast<const short8*>(&Bs[wn * 32 + 16 + l15][lg * 8]);
        acc[0][0] = __builtin_amdgcn_mfma_f32_16x16x32_bf16(a0, b0, acc[0][0], 0, 0, 0);
        acc[0][1] = __builtin_amdgcn_mfma_f32_16x16x32_bf16(a0, b1, acc[0][1], 0, 0, 0);
        acc[1][0] = __builtin_amdgcn_mfma_f32_16x16x32_bf16(a1, b0, acc[1][0], 0, 0, 0);
        acc[1][1] = __builtin_amdgcn_mfma_f32_16x16x32_bf16(a1, b1, acc[1][1], 0, 0, 0);
    }
    #pragma unroll
    for (int r = 0; r < 2; ++r)
        #pragma unroll
        for (int c = 0; c < 2; ++c)
            #pragma unroll
            for (int j = 0; j < 4; ++j) {
                int row = bm + wm * 32 + r * 16 + lg * 4 + j;
                int col = bn + wn * 32 + c * 16 + l15;
                float v = acc[r][c][j];
                if (F32OUT) reinterpret_cast<float*>(Cout)[(size_t)row * N + col] = v;
                else reinterpret_cast<ushort*>(Cout)[(size_t)row * N + col] = f2bf(v);
            }
}

// causal flash attention: Q,K,V in (B,S,H,HD) bf16; O in (B,S,D) bf16
// 1 wave per block, 16 q-rows per block, 32-key tiles
__global__ __launch_bounds__(64) void attn_kernel(const ushort* __restrict__ Qm,
        const ushort* __restrict__ Km, const ushort* __restrict__ Vm,
        ushort* __restrict__ Om) {
    __shared__ ushort Plds[16][40];
    __shared__ ushort Vt[128][40];  // [d][key]
    const int lane = threadIdx.x;
    const int qt = blockIdx.x;
    const int bh = blockIdx.y;
    const int b = bh >> 4, h = bh & 15;
    const int l15 = lane & 15, lg = lane >> 4;

    short8 qf[4];
    {
        int qrow = qt * 16 + l15;
        const ushort* qp = Qm + ((size_t)(b * S_ + qrow) * H_ + h) * HD_;
        #pragma unroll
        for (int c = 0; c < 4; ++c)
            qf[c] = *reinterpret_cast<const short8*>(qp + c * 32 + lg * 8);
    }
    f32x4 oacc[8] = {};
    float mrow[4], lrow[4];
    #pragma unroll
    for (int j = 0; j < 4; ++j) { mrow[j] = -1e30f; lrow[j] = 0.f; }

    const int ntiles = ((qt * 16 + 16) + 31) >> 5;
    const float scale = 0.08838834764831845f;  // 1/sqrt(128)

    for (int kt = 0; kt < ntiles; ++kt) {
        __syncthreads();
        // stage V tile transposed: Vt[d][key]
        {
            int row = lane & 31;
            int half = lane >> 5;
            #pragma unroll
            for (int it = 0; it < 8; ++it) {
                int c8 = (half * 8 + it) * 8;
                int4v v = *reinterpret_cast<const int4v*>(
                    Vm + ((size_t)(b * S_ + kt * 32 + row) * H_ + h) * HD_ + c8);
                const ushort* vp = reinterpret_cast<const ushort*>(&v);
                #pragma unroll
                for (int j = 0; j < 8; ++j) Vt[c8 + j][row] = vp[j];
            }
        }
        // S = Q @ K^T (two 16-col tiles)
        f32x4 sacc[2] = {};
        #pragma unroll
        for (int ct = 0; ct < 2; ++ct) {
            int krow = kt * 32 + ct * 16 + l15;
            const ushort* kp = Km + ((size_t)(b * S_ + krow) * H_ + h) * HD_;
            #pragma unroll
            for (int c = 0; c < 4; ++c) {
                short8 kf = *reinterpret_cast<const short8*>(kp + c * 32 + lg * 8);
                sacc[ct] = __builtin_amdgcn_mfma_f32_16x16x32_bf16(qf[c], kf, sacc[ct], 0, 0, 0);
            }
        }
        // online softmax (rows live in regs j; cols across the 16-lane group)
        #pragma unroll
        for (int j = 0; j < 4; ++j) {
            int qrow = qt * 16 + lg * 4 + j;
            float s0 = sacc[0][j] * scale;
            float s1 = sacc[1][j] * scale;
            int c0 = kt * 32 + l15;
            if (c0 > qrow) s0 = -1e30f;
            if (c0 + 16 > qrow) s1 = -1e30f;
            float mt = fmaxf(s0, s1);
            #pragma unroll
            for (int w = 1; w < 16; w <<= 1) mt = fmaxf(mt, __shfl_xor(mt, w));
            float mnew = fmaxf(mrow[j], mt);
            float corr = __expf(mrow[j] - mnew);
            float p0 = __expf(s0 - mnew);
            float p1 = __expf(s1 - mnew);
            float psum = p0 + p1;
            #pragma unroll
            for (int w = 1; w < 16; w <<= 1) psum += __shfl_xor(psum, w);
            lrow[j] = lrow[j] * corr + psum;
            mrow[j] = mnew;
            #pragma unroll
            for (int d = 0; d < 8; ++d) oacc[d][j] *= corr;
            Plds[lg * 4 + j][l15] = f2bf(p0);
            Plds[lg * 4 + j][16 + l15] = f2bf(p1);
        }
        __syncthreads();
        // O += P @ V
        short8 pf = *reinterpret_cast<const short8*>(&Plds[l15][lg * 8]);
        #pragma unroll
        for (int d = 0; d < 8; ++d) {
            short8 vf = *reinterpret_cast<const short8*>(&Vt[d * 16 + l15][lg * 8]);
            oacc[d] = __builtin_amdgcn_mfma_f32_16x16x32_bf16(pf, vf, oacc[d], 0, 0, 0);
        }
    }
    #pragma unroll
    for (int j = 0; j < 4; ++j) {
        int qrow = qt * 16 + lg * 4 + j;
        float inv = 1.0f / lrow[j];
        ushort* op = Om + ((size_t)(b * S_ + qrow)) * D_ + h * HD_;
        #pragma unroll
        for (int d = 0; d < 8; ++d)
            op[d * 16 + l15] = f2bf(oacc[d][j] * inv);
    }
}

extern "C" void kernel_launch(void* const* d_in, const int* in_sizes, int n_in,
                              void* d_out, int out_size, void* d_ws, size_t ws_size,
                              hipStream_t stream) {
    const float* x    = (const float*)d_in[0];
    const float* cosT = (const float*)d_in[1];
    const float* sinT = (const float*)d_in[2];
    const float* wq   = (const float*)d_in[3];
    const float* wk   = (const float*)d_in[4];
    const float* wv   = (const float*)d_in[5];
    const float* wo   = (const float*)d_in[6];
    float* out = (float*)d_out;

    char* ws = (char*)d_ws;
    const size_t szX = (size_t)B_ * S_ * D_ * 2;  // 16.78 MB
    const size_t szW = (size_t)D_ * D_ * 2;       // 8.39 MB
    ushort* xb  = (ushort*)(ws);
    ushort* wqb = (ushort*)(ws + szX);
    ushort* wkb = (ushort*)(ws + szX + szW);
    ushort* wvb = (ushort*)(ws + szX + 2 * szW);
    ushort* wob = (ushort*)(ws + szX + 3 * szW);
    ushort* q0  = (ushort*)(ws + szX + 4 * szW);
    ushort* k0  = (ushort*)(ws + szX + 4 * szW + szX);
    ushort* v0  = (ushort*)(ws + szX + 4 * szW + 2 * szX);
    ushort* att = xb;  // xb dead after the 3 QKV GEMMs; reuse as attention output

    const int nx = B_ * S_ * D_;  // 8388608
    const int nw = D_ * D_;       // 4194304
    cast_kernel<<<nx / 4 / 256, 256, 0, stream>>>(x, xb, nx / 4);
    cast_kernel<<<nw / 4 / 256, 256, 0, stream>>>(wq, wqb, nw / 4);
    cast_kernel<<<nw / 4 / 256, 256, 0, stream>>>(wk, wkb, nw / 4);
    cast_kernel<<<nw / 4 / 256, 256, 0, stream>>>(wv, wvb, nw / 4);
    cast_kernel<<<nw / 4 / 256, 256, 0, stream>>>(wo, wob, nw / 4);

    dim3 gg(D_ / 64, (B_ * S_) / 64);
    gemm_kernel<false><<<gg, 256, 0, stream>>>(xb, wqb, q0, B_ * S_, D_, D_);
    gemm_kernel<false><<<gg, 256, 0, stream>>>(xb, wkb, k0, B_ * S_, D_, D_);
    gemm_kernel<false><<<gg, 256, 0, stream>>>(xb, wvb, v0, B_ * S_, D_, D_);

    const int npairs = B_ * S_ * H_ * 64;  // one rotary pair per thread
    rope_kernel<<<npairs / 256, 256, 0, stream>>>(q0, cosT, sinT, npairs);
    rope_kernel<<<npairs / 256, 256, 0, stream>>>(v0, cosT, sinT, npairs);  // reference rotates v, not k

    attn_kernel<<<dim3(S_ / 16, B_ * H_), 64, 0, stream>>>(q0, k0, v0, att);

    gemm_kernel<true><<<gg, 256, 0, stream>>>(att, wob, out, B_ * S_, D_, D_);
}

// Round 2
// 623.436 us; speedup vs baseline: 1.7402x; 1.7402x over previous
//
#include <hip/hip_runtime.h>

typedef short short8 __attribute__((ext_vector_type(8)));
typedef float f32x4 __attribute__((ext_vector_type(4)));
typedef int int4v __attribute__((ext_vector_type(4)));

#define B_ 2
#define S_ 2048
#define D_ 2048
#define H_ 16
#define HD_ 128

#define GLL16(gp, lp) __builtin_amdgcn_global_load_lds( \
    (const __attribute__((address_space(1))) void*)(gp), \
    (__attribute__((address_space(3))) void*)(lp), 16, 0, 0)

__device__ inline ushort f2bf(float f) {
    union { float f; unsigned u; } v; v.f = f;
    unsigned r = v.u + 0x7FFFu + ((v.u >> 16) & 1u);
    return (ushort)(r >> 16);
}
__device__ inline float bf2f(ushort b) {
    union { unsigned u; float f; } v; v.u = ((unsigned)b) << 16;
    return v.f;
}

// fp32 -> bf16 cast, 4 elems/thread
__global__ void cast_kernel(const float* __restrict__ src, ushort* __restrict__ dst, int n4) {
    int i = blockIdx.x * blockDim.x + threadIdx.x;
    if (i >= n4) return;
    float4 v = reinterpret_cast<const float4*>(src)[i];
    ushort4 o;
    o.x = f2bf(v.x); o.y = f2bf(v.y); o.z = f2bf(v.z); o.w = f2bf(v.w);
    reinterpret_cast<ushort4*>(dst)[i] = o;
}

// w[K][N] f32 -> wT[N][K] bf16 via 64x64 LDS tile (one-time, not perf-critical)
__global__ __launch_bounds__(256) void cast_transpose_kernel(const float* __restrict__ src,
                                                             ushort* __restrict__ dst) {
    __shared__ ushort tile[64][72];
    const int bk = blockIdx.y * 64, bn = blockIdx.x * 64;
    const int t = threadIdx.x;
    #pragma unroll
    for (int it = 0; it < 4; ++it) {
        int id = t + it * 256;
        int row = id >> 4;
        int c4 = (id & 15) * 4;
        float4 v = *reinterpret_cast<const float4*>(&src[(size_t)(bk + row) * D_ + bn + c4]);
        ushort4 o; o.x = f2bf(v.x); o.y = f2bf(v.y); o.z = f2bf(v.z); o.w = f2bf(v.w);
        *reinterpret_cast<ushort4*>(&tile[row][c4]) = o;
    }
    __syncthreads();
    #pragma unroll
    for (int it = 0; it < 4; ++it) {
        int id = t + it * 256;
        int n = id >> 4;
        int c4 = (id & 15) * 4;
        ushort4 o;
        o.x = tile[c4 + 0][n]; o.y = tile[c4 + 1][n];
        o.z = tile[c4 + 2][n]; o.w = tile[c4 + 3][n];
        *reinterpret_cast<ushort4*>(&dst[(size_t)(bn + n) * D_ + bk + c4]) = o;
    }
}

// in-place RoPE on (B*H, S, HD) bf16, one (even,odd) pair per thread
__global__ void rope_kernel(ushort* __restrict__ t, const float* __restrict__ cosT,
                            const float* __restrict__ sinT, int npairs) {
    int pid = blockIdx.x * blockDim.x + threadIdx.x;
    if (pid >= npairs) return;
    int i = pid & 63;
    int s = (pid >> 6) & (S_ - 1);
    unsigned pr = reinterpret_cast<unsigned*>(t)[pid];
    float e = bf2f((ushort)(pr & 0xFFFFu));
    float o = bf2f((ushort)(pr >> 16));
    float c = cosT[s * 64 + i];
    float sn = sinT[s * 64 + i];
    float oe = e * c - o * sn;
    float oo = e * sn + o * c;
    unsigned outp = ((unsigned)f2bf(oo) << 16) | (unsigned)f2bf(oe);
    reinterpret_cast<unsigned*>(t)[pid] = outp;
}

// C = A[M][K] @ Bt[N][K]^T; m97 structure: 128x128 tile, BK=32, 4 waves,
// global_load_lds width 16 into linear LDS, 16 MFMA + 8 ds_read_b128 per K-step.
// PERM: write bf16 to (B,H,S,HD); F32OUT: write f32 row-major; else bf16 row-major.
template<bool F32OUT, bool PERM>
__global__ __launch_bounds__(256) void gemm2(const ushort* __restrict__ A,
        const ushort* __restrict__ Bt, void* __restrict__ Cout, int M, int N, int K) {
    __shared__ ushort As[128][32];
    __shared__ ushort Bs[128][32];
    const int tid = threadIdx.x, lane = tid & 63, wv = tid >> 6;
    const int wm = wv >> 1, wn = wv & 1;
    const int bm = blockIdx.y * 128, bn = blockIdx.x * 128;
    const int l15 = lane & 15, lg = lane >> 4;
    f32x4 acc[4][4] = {};
    // staging: wave w covers rows [w*32, w*32+32) of each 128x32 tile.
    // lane l -> row w*32 + i*16 + (l>>2), k-chunk (l&3)*8 shorts (16B); LDS dest linear.
    const int srow = wv * 32 + (lane >> 2);
    const int scol = (lane & 3) * 8;
    const ushort* ag = A + (size_t)(bm + srow) * K + scol;
    const ushort* bg = Bt + (size_t)(bn + srow) * K + scol;
    ushort* al = &As[wv * 32][0];
    ushort* bl = &Bs[wv * 32][0];
    const size_t row16 = (size_t)16 * K;

    for (int k0 = 0; k0 < K; k0 += 32) {
        __syncthreads();
        GLL16(ag + k0, al);
        GLL16(ag + k0 + row16, (char*)al + 1024);
        GLL16(bg + k0, bl);
        GLL16(bg + k0 + row16, (char*)bl + 1024);
        __syncthreads();
        short8 af[4], bf[4];
        #pragma unroll
        for (int i = 0; i < 4; ++i) {
            af[i] = *reinterpret_cast<const short8*>(&As[wm * 64 + i * 16 + l15][lg * 8]);
            bf[i] = *reinterpret_cast<const short8*>(&Bs[wn * 64 + i * 16 + l15][lg * 8]);
        }
        #pragma unroll
        for (int mi = 0; mi < 4; ++mi)
            #pragma unroll
            for (int ni = 0; ni < 4; ++ni)
                acc[mi][ni] = __builtin_amdgcn_mfma_f32_16x16x32_bf16(af[mi], bf[ni], acc[mi][ni], 0, 0, 0);
    }
    #pragma unroll
    for (int mi = 0; mi < 4; ++mi)
        #pragma unroll
        for (int ni = 0; ni < 4; ++ni)
            #pragma unroll
            for (int j = 0; j < 4; ++j) {
                int row = bm + wm * 64 + mi * 16 + lg * 4 + j;
                int col = bn + wn * 64 + ni * 16 + l15;
                float v = acc[mi][ni][j];
                if (F32OUT) {
                    reinterpret_cast<float*>(Cout)[(size_t)row * N + col] = v;
                } else if (PERM) {
                    int b = row >> 11, s = row & (S_ - 1);
                    int h = col >> 7, d = col & (HD_ - 1);
                    reinterpret_cast<ushort*>(Cout)[(((size_t)(b * H_ + h)) * S_ + s) * HD_ + d] = f2bf(v);
                } else {
                    reinterpret_cast<ushort*>(Cout)[(size_t)row * N + col] = f2bf(v);
                }
            }
}

// causal flash attention. Q,K,V in (B*H, S, HD) bf16; O in (B,S,D) bf16.
// 256 threads = 4 waves; block handles 64 q-rows (wave w: rows qt*64+w*16..+16);
// 64-key tiles: V staged transposed in LDS (shared), K read direct from global (L2).
__global__ __launch_bounds__(256) void attn2(const ushort* __restrict__ Qm,
        const ushort* __restrict__ Km, const ushort* __restrict__ Vm,
        ushort* __restrict__ Om) {
    __shared__ ushort Vt[128][72];     // [d][key], 2-way max on reads/writes
    __shared__ ushort Pl[4][16][72];   // per-wave P tile [qrow][key]
    const int tid = threadIdx.x, lane = tid & 63, wv = tid >> 6;
    const int l15 = lane & 15, lg = lane >> 4;
    const int qt = (int)(gridDim.x - 1) - (int)blockIdx.x;  // big blocks dispatched first
    const int bh = blockIdx.y;
    const size_t base = (size_t)bh * S_ * HD_;
    const int qrow0 = qt * 64 + wv * 16;

    short8 qf[4];
    {
        const ushort* qp = Qm + base + (size_t)(qrow0 + l15) * HD_;
        #pragma unroll
        for (int c = 0; c < 4; ++c)
            qf[c] = *reinterpret_cast<const short8*>(qp + c * 32 + lg * 8);
    }
    f32x4 oacc[8] = {};
    float mrow[4], lrow[4];
    #pragma unroll
    for (int j = 0; j < 4; ++j) { mrow[j] = -1e30f; lrow[j] = 0.f; }
    const float scale = 0.08838834764831845f;  // 1/sqrt(128)
    const int ntiles = qt + 1;

    for (int kt = 0; kt < ntiles; ++kt) {
        __syncthreads();
        // stage V tile transposed: lane -> key row (2B writes stride-2 => conflict-free)
        {
            const ushort* vp = Vm + base + (size_t)(kt * 64 + lane) * HD_ + wv * 32;
            #pragma unroll
            for (int cc = 0; cc < 4; ++cc) {
                int4v v = *reinterpret_cast<const int4v*>(vp + cc * 8);
                const ushort* e = reinterpret_cast<const ushort*>(&v);
                #pragma unroll
                for (int j = 0; j < 8; ++j) Vt[wv * 32 + cc * 8 + j][lane] = e[j];
            }
        }
        __syncthreads();
        // S = Q @ K^T : K frags direct from global (tile shared by 4 waves via L2)
        f32x4 sacc[4] = {};
        const ushort* kp0 = Km + base + (size_t)(kt * 64) * HD_;
        __builtin_amdgcn_s_setprio(1);
        #pragma unroll
        for (int ct = 0; ct < 4; ++ct) {
            const ushort* kp = kp0 + (size_t)(ct * 16 + l15) * HD_;
            #pragma unroll
            for (int c = 0; c < 4; ++c) {
                short8 kf = *reinterpret_cast<const short8*>(kp + c * 32 + lg * 8);
                sacc[ct] = __builtin_amdgcn_mfma_f32_16x16x32_bf16(qf[c], kf, sacc[ct], 0, 0, 0);
            }
        }
        __builtin_amdgcn_s_setprio(0);
        const bool dm = (kt == qt);  // only the diagonal tile needs masking
        #pragma unroll
        for (int j = 0; j < 4; ++j) {
            int qrow = qrow0 + lg * 4 + j;
            float s[4], p[4];
            #pragma unroll
            for (int ct = 0; ct < 4; ++ct) {
                s[ct] = sacc[ct][j] * scale;
                if (dm && (qt * 64 + ct * 16 + l15 > qrow)) s[ct] = -1e30f;
            }
            float mt = fmaxf(fmaxf(s[0], s[1]), fmaxf(s[2], s[3]));
            #pragma unroll
            for (int w = 1; w < 16; w <<= 1) mt = fmaxf(mt, __shfl_xor(mt, w));
            float mnew = fmaxf(mrow[j], mt);
            float corr = __expf(mrow[j] - mnew);
            float psum = 0.f;
            #pragma unroll
            for (int ct = 0; ct < 4; ++ct) { p[ct] = __expf(s[ct] - mnew); psum += p[ct]; }
            #pragma unroll
            for (int w = 1; w < 16; w <<= 1) psum += __shfl_xor(psum, w);
            lrow[j] = lrow[j] * corr + psum;
            mrow[j] = mnew;
            #pragma unroll
            for (int d = 0; d < 8; ++d) oacc[d][j] *= corr;
            #pragma unroll
            for (int ct = 0; ct < 4; ++ct)
                Pl[wv][lg * 4 + j][ct * 16 + l15] = f2bf(p[ct]);
        }
        // O += P @ V  (intra-wave LDS dep on Pl; compiler orders via lgkmcnt)
        __builtin_amdgcn_s_setprio(1);
        #pragma unroll
        for (int c2 = 0; c2 < 2; ++c2) {
            short8 pf = *reinterpret_cast<const short8*>(&Pl[wv][l15][c2 * 32 + lg * 8]);
            #pragma unroll
            for (int d = 0; d < 8; ++d) {
                short8 vf = *reinterpret_cast<const short8*>(&Vt[d * 16 + l15][c2 * 32 + lg * 8]);
                oacc[d] = __builtin_amdgcn_mfma_f32_16x16x32_bf16(pf, vf, oacc[d], 0, 0, 0);
            }
        }
        __builtin_amdgcn_s_setprio(0);
    }
    const int b = bh >> 4, h = bh & (H_ - 1);
    #pragma unroll
    for (int j = 0; j < 4; ++j) {
        int qrow = qt * 64 + wv * 16 + lg * 4 + j;
        float inv = 1.0f / lrow[j];
        ushort* op = Om + ((size_t)(b * S_ + qrow)) * D_ + h * HD_;
        #pragma unroll
        for (int d = 0; d < 8; ++d)
            op[d * 16 + l15] = f2bf(oacc[d][j] * inv);
    }
}

extern "C" void kernel_launch(void* const* d_in, const int* in_sizes, int n_in,
                              void* d_out, int out_size, void* d_ws, size_t ws_size,
                              hipStream_t stream) {
    const float* x    = (const float*)d_in[0];
    const float* cosT = (const float*)d_in[1];
    const float* sinT = (const float*)d_in[2];
    const float* wq   = (const float*)d_in[3];
    const float* wk   = (const float*)d_in[4];
    const float* wv   = (const float*)d_in[5];
    const float* wo   = (const float*)d_in[6];
    float* out = (float*)d_out;

    char* ws = (char*)d_ws;
    const size_t szX = (size_t)B_ * S_ * D_ * 2;  // 16.78 MB
    const size_t szW = (size_t)D_ * D_ * 2;       // 8.39 MB
    ushort* xb  = (ushort*)(ws);
    ushort* wqT = (ushort*)(ws + szX);
    ushort* wkT = (ushort*)(ws + szX + szW);
    ushort* wvT = (ushort*)(ws + szX + 2 * szW);
    ushort* woT = (ushort*)(ws + szX + 3 * szW);
    ushort* q0  = (ushort*)(ws + szX + 4 * szW);
    ushort* k0  = (ushort*)(ws + szX + 4 * szW + szX);
    ushort* v0  = (ushort*)(ws + szX + 4 * szW + 2 * szX);
    ushort* att = xb;  // xb dead after the 3 QKV GEMMs; reuse as attention output

    const int nx = B_ * S_ * D_;  // 8388608
    cast_kernel<<<nx / 4 / 256, 256, 0, stream>>>(x, xb, nx / 4);
    dim3 tg(D_ / 64, D_ / 64);
    cast_transpose_kernel<<<tg, 256, 0, stream>>>(wq, wqT);
    cast_transpose_kernel<<<tg, 256, 0, stream>>>(wk, wkT);
    cast_transpose_kernel<<<tg, 256, 0, stream>>>(wv, wvT);
    cast_transpose_kernel<<<tg, 256, 0, stream>>>(wo, woT);

    dim3 gg(D_ / 128, (B_ * S_) / 128);
    gemm2<false, true><<<gg, 256, 0, stream>>>(xb, wqT, q0, B_ * S_, D_, D_);
    gemm2<false, true><<<gg, 256, 0, stream>>>(xb, wkT, k0, B_ * S_, D_, D_);
    gemm2<false, true><<<gg, 256, 0, stream>>>(xb, wvT, v0, B_ * S_, D_, D_);

    const int npairs = B_ * S_ * H_ * 64;
    rope_kernel<<<npairs / 256, 256, 0, stream>>>(q0, cosT, sinT, npairs);
    rope_kernel<<<npairs / 256, 256, 0, stream>>>(v0, cosT, sinT, npairs);  // reference rotates v, not k

    attn2<<<dim3(S_ / 64, B_ * H_), 256, 0, stream>>>(q0, k0, v0, att);

    gemm2<true, false><<<gg, 256, 0, stream>>>(att, woT, out, B_ * S_, D_, D_);
}

// Round 3
// 363.856 us; speedup vs baseline: 2.9817x; 1.7134x over previous
//
#include <hip/hip_runtime.h>

typedef short short8 __attribute__((ext_vector_type(8)));
typedef float f32x4 __attribute__((ext_vector_type(4)));
typedef int int4v __attribute__((ext_vector_type(4)));

#define B_ 2
#define S_ 2048
#define D_ 2048
#define H_ 16
#define HD_ 128

#define GLL16(gp, lp) __builtin_amdgcn_global_load_lds( \
    (const __attribute__((address_space(1))) void*)(gp), \
    (__attribute__((address_space(3))) void*)(lp), 16, 0, 0)

__device__ inline ushort f2bf(float f) {
    union { float f; unsigned u; } v; v.f = f;
    unsigned r = v.u + 0x7FFFu + ((v.u >> 16) & 1u);
    return (ushort)(r >> 16);
}
__device__ inline float bf2f(ushort b) {
    union { unsigned u; float f; } v; v.u = ((unsigned)b) << 16;
    return v.f;
}

// fp32 -> bf16 cast, 4 elems/thread
__global__ void cast_kernel(const float* __restrict__ src, ushort* __restrict__ dst, int n4) {
    int i = blockIdx.x * blockDim.x + threadIdx.x;
    if (i >= n4) return;
    float4 v = reinterpret_cast<const float4*>(src)[i];
    ushort4 o;
    o.x = f2bf(v.x); o.y = f2bf(v.y); o.z = f2bf(v.z); o.w = f2bf(v.w);
    reinterpret_cast<ushort4*>(dst)[i] = o;
}

// w[K][N] f32 -> wT[N][K] bf16 via 64x64 LDS tile (one-time, not perf-critical)
__global__ __launch_bounds__(256) void cast_transpose_kernel(const float* __restrict__ src,
                                                             ushort* __restrict__ dst) {
    __shared__ ushort tile[64][72];
    const int bk = blockIdx.y * 64, bn = blockIdx.x * 64;
    const int t = threadIdx.x;
    #pragma unroll
    for (int it = 0; it < 4; ++it) {
        int id = t + it * 256;
        int row = id >> 4;
        int c4 = (id & 15) * 4;
        float4 v = *reinterpret_cast<const float4*>(&src[(size_t)(bk + row) * D_ + bn + c4]);
        ushort4 o; o.x = f2bf(v.x); o.y = f2bf(v.y); o.z = f2bf(v.z); o.w = f2bf(v.w);
        *reinterpret_cast<ushort4*>(&tile[row][c4]) = o;
    }
    __syncthreads();
    #pragma unroll
    for (int it = 0; it < 4; ++it) {
        int id = t + it * 256;
        int n = id >> 4;
        int c4 = (id & 15) * 4;
        ushort4 o;
        o.x = tile[c4 + 0][n]; o.y = tile[c4 + 1][n];
        o.z = tile[c4 + 2][n]; o.w = tile[c4 + 3][n];
        *reinterpret_cast<ushort4*>(&dst[(size_t)(bn + n) * D_ + bk + c4]) = o;
    }
}

// in-place RoPE on (B*H, S, HD) bf16, one (even,odd) pair per thread
__global__ void rope_kernel(ushort* __restrict__ t, const float* __restrict__ cosT,
                            const float* __restrict__ sinT, int npairs) {
    int pid = blockIdx.x * blockDim.x + threadIdx.x;
    if (pid >= npairs) return;
    int i = pid & 63;
    int s = (pid >> 6) & (S_ - 1);
    unsigned pr = reinterpret_cast<unsigned*>(t)[pid];
    float e = bf2f((ushort)(pr & 0xFFFFu));
    float o = bf2f((ushort)(pr >> 16));
    float c = cosT[s * 64 + i];
    float sn = sinT[s * 64 + i];
    float oe = e * c - o * sn;
    float oo = e * sn + o * c;
    unsigned outp = ((unsigned)f2bf(oo) << 16) | (unsigned)f2bf(oe);
    reinterpret_cast<unsigned*>(t)[pid] = outp;
}

// C = A[M][K] @ Bt[N][K]^T; m97 structure: 128x128 tile, BK=32, 4 waves.
template<bool F32OUT, bool PERM>
__global__ __launch_bounds__(256) void gemm2(const ushort* __restrict__ A,
        const ushort* __restrict__ Bt, void* __restrict__ Cout, int M, int N, int K) {
    __shared__ ushort As[128][32];
    __shared__ ushort Bs[128][32];
    const int tid = threadIdx.x, lane = tid & 63, wv = tid >> 6;
    const int wm = wv >> 1, wn = wv & 1;
    const int bm = blockIdx.y * 128, bn = blockIdx.x * 128;
    const int l15 = lane & 15, lg = lane >> 4;
    f32x4 acc[4][4] = {};
    const int srow = wv * 32 + (lane >> 2);
    const int scol = (lane & 3) * 8;
    const ushort* ag = A + (size_t)(bm + srow) * K + scol;
    const ushort* bg = Bt + (size_t)(bn + srow) * K + scol;
    ushort* al = &As[wv * 32][0];
    ushort* bl = &Bs[wv * 32][0];
    const size_t row16 = (size_t)16 * K;

    for (int k0 = 0; k0 < K; k0 += 32) {
        __syncthreads();
        GLL16(ag + k0, al);
        GLL16(ag + k0 + row16, (char*)al + 1024);
        GLL16(bg + k0, bl);
        GLL16(bg + k0 + row16, (char*)bl + 1024);
        __syncthreads();
        short8 af[4], bf[4];
        #pragma unroll
        for (int i = 0; i < 4; ++i) {
            af[i] = *reinterpret_cast<const short8*>(&As[wm * 64 + i * 16 + l15][lg * 8]);
            bf[i] = *reinterpret_cast<const short8*>(&Bs[wn * 64 + i * 16 + l15][lg * 8]);
        }
        #pragma unroll
        for (int mi = 0; mi < 4; ++mi)
            #pragma unroll
            for (int ni = 0; ni < 4; ++ni)
                acc[mi][ni] = __builtin_amdgcn_mfma_f32_16x16x32_bf16(af[mi], bf[ni], acc[mi][ni], 0, 0, 0);
    }
    #pragma unroll
    for (int mi = 0; mi < 4; ++mi)
        #pragma unroll
        for (int ni = 0; ni < 4; ++ni)
            #pragma unroll
            for (int j = 0; j < 4; ++j) {
                int row = bm + wm * 64 + mi * 16 + lg * 4 + j;
                int col = bn + wn * 64 + ni * 16 + l15;
                float v = acc[mi][ni][j];
                if (F32OUT) {
                    reinterpret_cast<float*>(Cout)[(size_t)row * N + col] = v;
                } else if (PERM) {
                    int b = row >> 11, s = row & (S_ - 1);
                    int h = col >> 7, d = col & (HD_ - 1);
                    reinterpret_cast<ushort*>(Cout)[(((size_t)(b * H_ + h)) * S_ + s) * HD_ + d] = f2bf(v);
                } else {
                    reinterpret_cast<ushort*>(Cout)[(size_t)row * N + col] = f2bf(v);
                }
            }
}

// causal flash attention, pipelined. Q,K,V in (B*H, S, HD) bf16; O in (B,S,D) bf16.
// 4 waves, 64 q-rows/block (wave w: rows qt*64+w*16..+16), 64-key tiles.
// K: double-buffered LDS via global_load_lds with pre-swizzled source
//    (layout byte = row*256 + (col ^ ((row&7)<<4))); prefetch issued at top of tile.
// V: T14 split — register loads at top, transpose-write into Vt[cur^1] after PV.
__global__ __launch_bounds__(256) void attn3(const ushort* __restrict__ Qm,
        const ushort* __restrict__ Km, const ushort* __restrict__ Vm,
        ushort* __restrict__ Om) {
    __shared__ ushort Kb[2][64 * 128];   // swizzled [key][d], 16KB each
    __shared__ ushort Vt[2][128][72];    // [d][key]
    __shared__ ushort Pl[4][16][72];     // per-wave P tile [qrow][key]
    const int tid = threadIdx.x, lane = tid & 63, wv = tid >> 6;
    const int l15 = lane & 15, lg = lane >> 4;
    const int qt = 31 - (int)blockIdx.y;   // heavy tiles dispatch first
    const int bh = blockIdx.x;
    const size_t base = (size_t)bh * S_ * HD_;
    const int qrow0 = qt * 64 + wv * 16;

    short8 qf[4];
    {
        const ushort* qp = Qm + base + (size_t)(qrow0 + l15) * HD_;
        #pragma unroll
        for (int c = 0; c < 4; ++c)
            qf[c] = *reinterpret_cast<const short8*>(qp + c * 32 + lg * 8);
    }
    f32x4 oacc[8] = {};
    float mrow[4], lrow[4];
    #pragma unroll
    for (int j = 0; j < 4; ++j) { mrow[j] = -1e30f; lrow[j] = 0.f; }
    const float scale = 0.08838834764831845f;  // 1/sqrt(128)
    const int ntiles = qt + 1;

    // prologue: stage tile 0
    {
        #pragma unroll
        for (int c = 0; c < 4; ++c) {
            int row = wv * 16 + c * 4 + (lane >> 4);
            GLL16(Km + base + (size_t)row * HD_ + (((lane & 15) ^ (row & 7)) << 3),
                  &Kb[0][wv * 2048 + c * 512]);
        }
        const ushort* vp = Vm + base + (size_t)lane * HD_ + wv * 32;
        #pragma unroll
        for (int cc = 0; cc < 4; ++cc) {
            int4v v = *reinterpret_cast<const int4v*>(vp + cc * 8);
            const ushort* e = reinterpret_cast<const ushort*>(&v);
            #pragma unroll
            for (int j = 0; j < 8; ++j) Vt[0][wv * 32 + cc * 8 + j][lane] = e[j];
        }
    }
    __syncthreads();

    int cur = 0;
    for (int kt = 0; kt < ntiles; ++kt) {
        const bool pfn = (kt + 1 < ntiles);
        int4v vr[4];
        // issue next-tile prefetch FIRST: latency hides under this tile's compute
        if (pfn) {
            const int r0 = (kt + 1) * 64;
            #pragma unroll
            for (int c = 0; c < 4; ++c) {
                int row = wv * 16 + c * 4 + (lane >> 4);
                GLL16(Km + base + (size_t)(r0 + row) * HD_ + (((lane & 15) ^ (row & 7)) << 3),
                      &Kb[cur ^ 1][wv * 2048 + c * 512]);
            }
            const ushort* vp = Vm + base + (size_t)(r0 + lane) * HD_ + wv * 32;
            #pragma unroll
            for (int cc = 0; cc < 4; ++cc)
                vr[cc] = *reinterpret_cast<const int4v*>(vp + cc * 8);
        }
        // S = Q @ K^T from swizzled LDS
        f32x4 sacc[4] = {};
        const ushort* Kc = &Kb[cur][0];
        __builtin_amdgcn_s_setprio(1);
        #pragma unroll
        for (int ct = 0; ct < 4; ++ct) {
            const int row = ct * 16 + l15;
            const int sw = (row & 7) << 3;
            #pragma unroll
            for (int c = 0; c < 4; ++c) {
                short8 kf = *reinterpret_cast<const short8*>(
                    Kc + row * 128 + ((c * 32 + lg * 8) ^ sw));
                sacc[ct] = __builtin_amdgcn_mfma_f32_16x16x32_bf16(qf[c], kf, sacc[ct], 0, 0, 0);
            }
        }
        __builtin_amdgcn_s_setprio(0);
        // online softmax
        const bool dm = (kt == qt);
        #pragma unroll
        for (int j = 0; j < 4; ++j) {
            int qrow = qrow0 + lg * 4 + j;
            float s[4], p[4];
            #pragma unroll
            for (int ct = 0; ct < 4; ++ct) {
                s[ct] = sacc[ct][j] * scale;
                if (dm && (qt * 64 + ct * 16 + l15 > qrow)) s[ct] = -1e30f;
            }
            float mt = fmaxf(fmaxf(s[0], s[1]), fmaxf(s[2], s[3]));
            #pragma unroll
            for (int w = 1; w < 16; w <<= 1) mt = fmaxf(mt, __shfl_xor(mt, w));
            float mnew = fmaxf(mrow[j], mt);
            float corr = __expf(mrow[j] - mnew);
            float psum = 0.f;
            #pragma unroll
            for (int ct = 0; ct < 4; ++ct) { p[ct] = __expf(s[ct] - mnew); psum += p[ct]; }
            #pragma unroll
            for (int w = 1; w < 16; w <<= 1) psum += __shfl_xor(psum, w);
            lrow[j] = lrow[j] * corr + psum;
            mrow[j] = mnew;
            #pragma unroll
            for (int d = 0; d < 8; ++d) oacc[d][j] *= corr;
            #pragma unroll
            for (int ct = 0; ct < 4; ++ct)
                Pl[wv][lg * 4 + j][ct * 16 + l15] = f2bf(p[ct]);
        }
        // O += P @ V (Pl intra-wave dep via lgkmcnt; Vt[cur] barrier'd last iter)
        __builtin_amdgcn_s_setprio(1);
        #pragma unroll
        for (int c2 = 0; c2 < 2; ++c2) {
            short8 pfr = *reinterpret_cast<const short8*>(&Pl[wv][l15][c2 * 32 + lg * 8]);
            #pragma unroll
            for (int d = 0; d < 8; ++d) {
                short8 vf = *reinterpret_cast<const short8*>(&Vt[cur][d * 16 + l15][c2 * 32 + lg * 8]);
                oacc[d] = __builtin_amdgcn_mfma_f32_16x16x32_bf16(pfr, vf, oacc[d], 0, 0, 0);
            }
        }
        __builtin_amdgcn_s_setprio(0);
        // late write of prefetched V into the other buffer
        if (pfn) {
            #pragma unroll
            for (int cc = 0; cc < 4; ++cc) {
                const ushort* e = reinterpret_cast<const ushort*>(&vr[cc]);
                #pragma unroll
                for (int j = 0; j < 8; ++j) Vt[cur ^ 1][wv * 32 + cc * 8 + j][lane] = e[j];
            }
        }
        __syncthreads();
        cur ^= 1;
    }
    const int b = bh >> 4, h = bh & (H_ - 1);
    #pragma unroll
    for (int j = 0; j < 4; ++j) {
        int qrow = qt * 64 + wv * 16 + lg * 4 + j;
        float inv = 1.0f / lrow[j];
        ushort* op = Om + ((size_t)(b * S_ + qrow)) * D_ + h * HD_;
        #pragma unroll
        for (int d = 0; d < 8; ++d)
            op[d * 16 + l15] = f2bf(oacc[d][j] * inv);
    }
}

extern "C" void kernel_launch(void* const* d_in, const int* in_sizes, int n_in,
                              void* d_out, int out_size, void* d_ws, size_t ws_size,
                              hipStream_t stream) {
    const float* x    = (const float*)d_in[0];
    const float* cosT = (const float*)d_in[1];
    const float* sinT = (const float*)d_in[2];
    const float* wq   = (const float*)d_in[3];
    const float* wk   = (const float*)d_in[4];
    const float* wv   = (const float*)d_in[5];
    const float* wo   = (const float*)d_in[6];
    float* out = (float*)d_out;

    char* ws = (char*)d_ws;
    const size_t szX = (size_t)B_ * S_ * D_ * 2;  // 16.78 MB
    const size_t szW = (size_t)D_ * D_ * 2;       // 8.39 MB
    ushort* xb  = (ushort*)(ws);
    ushort* wqT = (ushort*)(ws + szX);
    ushort* wkT = (ushort*)(ws + szX + szW);
    ushort* wvT = (ushort*)(ws + szX + 2 * szW);
    ushort* woT = (ushort*)(ws + szX + 3 * szW);
    ushort* q0  = (ushort*)(ws + szX + 4 * szW);
    ushort* k0  = (ushort*)(ws + szX + 4 * szW + szX);
    ushort* v0  = (ushort*)(ws + szX + 4 * szW + 2 * szX);
    ushort* att = xb;  // xb dead after the 3 QKV GEMMs; reuse as attention output

    const int nx = B_ * S_ * D_;  // 8388608
    cast_kernel<<<nx / 4 / 256, 256, 0, stream>>>(x, xb, nx / 4);
    dim3 tg(D_ / 64, D_ / 64);
    cast_transpose_kernel<<<tg, 256, 0, stream>>>(wq, wqT);
    cast_transpose_kernel<<<tg, 256, 0, stream>>>(wk, wkT);
    cast_transpose_kernel<<<tg, 256, 0, stream>>>(wv, wvT);
    cast_transpose_kernel<<<tg, 256, 0, stream>>>(wo, woT);

    dim3 gg(D_ / 128, (B_ * S_) / 128);
    gemm2<false, true><<<gg, 256, 0, stream>>>(xb, wqT, q0, B_ * S_, D_, D_);
    gemm2<false, true><<<gg, 256, 0, stream>>>(xb, wkT, k0, B_ * S_, D_, D_);
    gemm2<false, true><<<gg, 256, 0, stream>>>(xb, wvT, v0, B_ * S_, D_, D_);

    const int npairs = B_ * S_ * H_ * 64;
    rope_kernel<<<npairs / 256, 256, 0, stream>>>(q0, cosT, sinT, npairs);
    rope_kernel<<<npairs / 256, 256, 0, stream>>>(v0, cosT, sinT, npairs);  // reference rotates v, not k

    attn3<<<dim3(B_ * H_, S_ / 64), 256, 0, stream>>>(q0, k0, v0, att);

    gemm2<true, false><<<gg, 256, 0, stream>>>(att, woT, out, B_ * S_, D_, D_);
}

// Round 4
// 306.214 us; speedup vs baseline: 3.5430x; 1.1882x over previous
//
#include <hip/hip_runtime.h>

typedef short short8 __attribute__((ext_vector_type(8)));
typedef float f32x4 __attribute__((ext_vector_type(4)));
typedef int int4v __attribute__((ext_vector_type(4)));

#define B_ 2
#define S_ 2048
#define D_ 2048
#define H_ 16
#define HD_ 128
#define K_ 2048   // GEMM K (both projections)

#define GLL16(gp, lp) __builtin_amdgcn_global_load_lds( \
    (const __attribute__((address_space(1))) void*)(gp), \
    (__attribute__((address_space(3))) void*)(lp), 16, 0, 0)

__device__ inline ushort f2bf(float f) {
    union { float f; unsigned u; } v; v.f = f;
    unsigned r = v.u + 0x7FFFu + ((v.u >> 16) & 1u);
    return (ushort)(r >> 16);
}
__device__ inline float bf2f(ushort b) {
    union { unsigned u; float f; } v; v.u = ((unsigned)b) << 16;
    return v.f;
}

// fp32 -> bf16 cast, 4 elems/thread
__global__ void cast_kernel(const float* __restrict__ src, ushort* __restrict__ dst, int n4) {
    int i = blockIdx.x * blockDim.x + threadIdx.x;
    if (i >= n4) return;
    float4 v = reinterpret_cast<const float4*>(src)[i];
    ushort4 o;
    o.x = f2bf(v.x); o.y = f2bf(v.y); o.z = f2bf(v.z); o.w = f2bf(v.w);
    reinterpret_cast<ushort4*>(dst)[i] = o;
}

// w[K][N] f32 -> wT[N][K] bf16 via 64x64 LDS tile (one-time)
__global__ __launch_bounds__(256) void cast_transpose_kernel(const float* __restrict__ src,
                                                             ushort* __restrict__ dst) {
    __shared__ ushort tile[64][72];
    const int bk = blockIdx.y * 64, bn = blockIdx.x * 64;
    const int t = threadIdx.x;
    #pragma unroll
    for (int it = 0; it < 4; ++it) {
        int id = t + it * 256;
        int row = id >> 4;
        int c4 = (id & 15) * 4;
        float4 v = *reinterpret_cast<const float4*>(&src[(size_t)(bk + row) * D_ + bn + c4]);
        ushort4 o; o.x = f2bf(v.x); o.y = f2bf(v.y); o.z = f2bf(v.z); o.w = f2bf(v.w);
        *reinterpret_cast<ushort4*>(&tile[row][c4]) = o;
    }
    __syncthreads();
    #pragma unroll
    for (int it = 0; it < 4; ++it) {
        int id = t + it * 256;
        int n = id >> 4;
        int c4 = (id & 15) * 4;
        ushort4 o;
        o.x = tile[c4 + 0][n]; o.y = tile[c4 + 1][n];
        o.z = tile[c4 + 2][n]; o.w = tile[c4 + 3][n];
        *reinterpret_cast<ushort4*>(&dst[(size_t)(bn + n) * D_ + bk + c4]) = o;
    }
}

// in-place RoPE on (B*H, S, HD) bf16, one (even,odd) pair per thread
__global__ void rope_kernel(ushort* __restrict__ t, const float* __restrict__ cosT,
                            const float* __restrict__ sinT, int npairs) {
    int pid = blockIdx.x * blockDim.x + threadIdx.x;
    if (pid >= npairs) return;
    int i = pid & 63;
    int s = (pid >> 6) & (S_ - 1);
    unsigned pr = reinterpret_cast<unsigned*>(t)[pid];
    float e = bf2f((ushort)(pr & 0xFFFFu));
    float o = bf2f((ushort)(pr >> 16));
    float c = cosT[s * 64 + i];
    float sn = sinT[s * 64 + i];
    float oe = e * c - o * sn;
    float oo = e * sn + o * c;
    unsigned outp = ((unsigned)f2bf(oo) << 16) | (unsigned)f2bf(oe);
    reinterpret_cast<unsigned*>(t)[pid] = outp;
}

// ===================== 256x256 8-phase GEMM (T1+T2+T3+T4+T5) =====================
// C[4096][N] = A[4096][2048] @ Bt[N][2048]^T, bf16 in, fp32 acc.
// 8 waves (2Mx4N), per-wave 128x64 output, BK=64, 2 K-tiles per iteration.
// LDS 128KB dynamic: buf b at b*65536: A [2 halves][128][64] then B at +32768.
// Both-sides swizzle: LDS byte col ^= (row&7)<<4 (stage via pre-swizzled global src).
// MODE 0: N=6144 fused QKV -> bf16 (B*H,S,HD) into q0/k0/v0.  MODE 1: N=2048 -> f32.
#define BAR8() __builtin_amdgcn_s_barrier()
#define VMC2() asm volatile("s_waitcnt vmcnt(2)" ::: "memory")

template<int MODE>
__global__ __launch_bounds__(512, 2) void gemm8(const ushort* __restrict__ A,
        const ushort* __restrict__ Bt, ushort* __restrict__ q0, ushort* __restrict__ k0,
        ushort* __restrict__ v0, float* __restrict__ outf, int nbx) {
    extern __shared__ char smem[];
    const int tid = threadIdx.x, lane = tid & 63, wv = tid >> 6;
    const int wm = wv >> 2, wn = wv & 3;
    const int l15 = lane & 15, lg = lane >> 4;
    // bijective XCD swizzle (gridDim.x % 8 == 0 for both modes)
    const int nwg = (int)gridDim.x, cpx = nwg >> 3;
    const int swzb = ((int)blockIdx.x & 7) * cpx + ((int)blockIdx.x >> 3);
    const int bn = (swzb % nbx) * 256, bm = (swzb / nbx) * 256;

    f32x4 acc[8][4] = {};

    // staging addresses: lane covers row (wv*8 + lane>>3) of a 64-row round,
    // 16B chunk pre-swizzled: chunk = (lane&7) ^ ((lane>>3)&7)  [= (row&7)]
    const int grl = wv * 8 + (lane >> 3);
    const int swc = (((lane & 7) ^ ((lane >> 3) & 7)) * 8);
    const ushort* Ag = A + (size_t)(bm + grl) * K_ + swc;
    const ushort* Bg = Bt + (size_t)(bn + grl) * K_ + swc;
    const size_t rowH = (size_t)128 * K_;   // half stride (rows)
    const size_t row64 = (size_t)64 * K_;   // round stride

#define STAGE_A(t, h) do { if ((t) < 32) { \
        const ushort* g = Ag + (size_t)(h) * rowH + (size_t)(t) * 64; \
        char* l = smem + (((t) & 1) << 16) + ((h) << 14) + (wv << 10); \
        GLL16(g, l); GLL16(g + row64, l + 8192); } } while (0)
#define STAGE_B(t, h) do { if ((t) < 32) { \
        const ushort* g = Bg + (size_t)(h) * rowH + (size_t)(t) * 64; \
        char* l = smem + (((t) & 1) << 16) + 32768 + ((h) << 14) + (wv << 10); \
        GLL16(g, l); GLL16(g + row64, l + 8192); } } while (0)

    // register-subtile ds_reads (compiler emits ds_read_b128 + its own lgkmcnt)
    const int colsw0 = (lg * 16) ^ ((l15 & 7) << 4);
    const int colsw1 = (64 + lg * 16) ^ ((l15 & 7) << 4);
    const char* abase0 = smem + (wm << 14);                     // buf0 A
    const char* bbase0 = smem + 32768 + ((wn >> 1) << 14);      // buf0 B
    const char* abase1 = abase0 + 65536;
    const char* bbase1 = bbase0 + 65536;
    const int brow = ((wn & 1) * 64 + l15) * 128;               // + c*2048

#define LDA(ab, q, cs) do { _Pragma("unroll") for (int f = 0; f < 4; ++f) \
        a[f] = *reinterpret_cast<const short8*>((ab) + ((q) * 64 + f * 16 + l15) * 128 + (cs)); } while (0)
#define LDB(bb, cs) do { _Pragma("unroll") for (int c = 0; c < 4; ++c) \
        b[c] = *reinterpret_cast<const short8*>((bb) + brow + c * 2048 + (cs)); } while (0)
#define MM(q) do { __builtin_amdgcn_s_setprio(1); \
        _Pragma("unroll") for (int f = 0; f < 4; ++f) \
        _Pragma("unroll") for (int c = 0; c < 4; ++c) \
            acc[(q) * 4 + f][c] = __builtin_amdgcn_mfma_f32_16x16x32_bf16(a[f], b[c], acc[(q) * 4 + f][c], 0, 0, 0); \
        __builtin_amdgcn_s_setprio(0); } while (0)

    // prologue: tile0 fully + tile1 B-half0; wait all but newest half
    STAGE_A(0, 0); STAGE_A(0, 1); STAGE_B(0, 0); STAGE_B(0, 1);
    STAGE_B(1, 0);
    VMC2();
    BAR8();

    for (int i = 0; i < 16; ++i) {
        const int t1 = 2 * i + 1, s0 = 2 * i + 2, s1 = 2 * i + 3;
        short8 a[4], b[4];
        // ph1: tile 2i (buf0), rows q0, k0
        LDB(bbase0, colsw0); LDA(abase0, 0, colsw0);
        STAGE_A(t1, 0);
        BAR8(); MM(0); BAR8();
        // ph2: q1 k0
        LDA(abase0, 1, colsw0);
        STAGE_A(t1, 1);
        BAR8(); MM(1); BAR8();
        // ph3: q0 k1
        LDB(bbase0, colsw1); LDA(abase0, 0, colsw1);
        STAGE_B(t1, 1);
        BAR8(); MM(0); BAR8();
        // ph4: q1 k1 ; ensure tile (2i+1) resident before ph5
        LDA(abase0, 1, colsw1);
        STAGE_B(s0, 0);
        VMC2();
        BAR8(); MM(1); BAR8();
        // ph5: tile 2i+1 (buf1), q0 k0
        LDB(bbase1, colsw0); LDA(abase1, 0, colsw0);
        STAGE_A(s0, 0);
        BAR8(); MM(0); BAR8();
        // ph6: q1 k0
        LDA(abase1, 1, colsw0);
        STAGE_A(s0, 1);
        BAR8(); MM(1); BAR8();
        // ph7: q0 k1
        LDB(bbase1, colsw1); LDA(abase1, 0, colsw1);
        STAGE_B(s0, 1);
        BAR8(); MM(0); BAR8();
        // ph8: q1 k1 ; ensure tile (2i+2) resident before next ph1
        LDA(abase1, 1, colsw1);
        STAGE_B(s1, 0);
        VMC2();
        BAR8(); MM(1); BAR8();
    }

    // epilogue
    const int colbase = bn + wn * 64;
    if (MODE == 0) {
        const int seg = colbase >> 11;  // uniform per block (bn 256-aligned)
        ushort* segp = (seg == 0) ? q0 : ((seg == 1) ? k0 : v0);
        #pragma unroll
        for (int rf = 0; rf < 8; ++rf)
            #pragma unroll
            for (int c = 0; c < 4; ++c)
                #pragma unroll
                for (int j = 0; j < 4; ++j) {
                    int row = bm + wm * 128 + rf * 16 + lg * 4 + j;
                    int col = colbase + c * 16 + l15;
                    int bb = row >> 11, s = row & (S_ - 1);
                    int h = (col >> 7) & (H_ - 1), d = col & (HD_ - 1);
                    segp[(((size_t)(bb * H_ + h)) * S_ + s) * HD_ + d] = f2bf(acc[rf][c][j]);
                }
    } else {
        #pragma unroll
        for (int rf = 0; rf < 8; ++rf)
            #pragma unroll
            for (int c = 0; c < 4; ++c)
                #pragma unroll
                for (int j = 0; j < 4; ++j) {
                    int row = bm + wm * 128 + rf * 16 + lg * 4 + j;
                    int col = colbase + c * 16 + l15;
                    outf[(size_t)row * D_ + col] = acc[rf][c][j];
                }
    }
#undef STAGE_A
#undef STAGE_B
#undef LDA
#undef LDB
#undef MM
}

// causal flash attention, pipelined (round-3 version, unchanged).
__global__ __launch_bounds__(256) void attn3(const ushort* __restrict__ Qm,
        const ushort* __restrict__ Km, const ushort* __restrict__ Vm,
        ushort* __restrict__ Om) {
    __shared__ ushort Kb[2][64 * 128];   // swizzled [key][d]
    __shared__ ushort Vt[2][128][72];    // [d][key]
    __shared__ ushort Pl[4][16][72];     // per-wave P tile
    const int tid = threadIdx.x, lane = tid & 63, wv = tid >> 6;
    const int l15 = lane & 15, lg = lane >> 4;
    const int qt = 31 - (int)blockIdx.y;
    const int bh = blockIdx.x;
    const size_t base = (size_t)bh * S_ * HD_;
    const int qrow0 = qt * 64 + wv * 16;

    short8 qf[4];
    {
        const ushort* qp = Qm + base + (size_t)(qrow0 + l15) * HD_;
        #pragma unroll
        for (int c = 0; c < 4; ++c)
            qf[c] = *reinterpret_cast<const short8*>(qp + c * 32 + lg * 8);
    }
    f32x4 oacc[8] = {};
    float mrow[4], lrow[4];
    #pragma unroll
    for (int j = 0; j < 4; ++j) { mrow[j] = -1e30f; lrow[j] = 0.f; }
    const float scale = 0.08838834764831845f;
    const int ntiles = qt + 1;

    {
        #pragma unroll
        for (int c = 0; c < 4; ++c) {
            int row = wv * 16 + c * 4 + (lane >> 4);
            GLL16(Km + base + (size_t)row * HD_ + (((lane & 15) ^ (row & 7)) << 3),
                  &Kb[0][wv * 2048 + c * 512]);
        }
        const ushort* vp = Vm + base + (size_t)lane * HD_ + wv * 32;
        #pragma unroll
        for (int cc = 0; cc < 4; ++cc) {
            int4v v = *reinterpret_cast<const int4v*>(vp + cc * 8);
            const ushort* e = reinterpret_cast<const ushort*>(&v);
            #pragma unroll
            for (int j = 0; j < 8; ++j) Vt[0][wv * 32 + cc * 8 + j][lane] = e[j];
        }
    }
    __syncthreads();

    int cur = 0;
    for (int kt = 0; kt < ntiles; ++kt) {
        const bool pfn = (kt + 1 < ntiles);
        int4v vr[4];
        if (pfn) {
            const int r0 = (kt + 1) * 64;
            #pragma unroll
            for (int c = 0; c < 4; ++c) {
                int row = wv * 16 + c * 4 + (lane >> 4);
                GLL16(Km + base + (size_t)(r0 + row) * HD_ + (((lane & 15) ^ (row & 7)) << 3),
                      &Kb[cur ^ 1][wv * 2048 + c * 512]);
            }
            const ushort* vp = Vm + base + (size_t)(r0 + lane) * HD_ + wv * 32;
            #pragma unroll
            for (int cc = 0; cc < 4; ++cc)
                vr[cc] = *reinterpret_cast<const int4v*>(vp + cc * 8);
        }
        f32x4 sacc[4] = {};
        const ushort* Kc = &Kb[cur][0];
        __builtin_amdgcn_s_setprio(1);
        #pragma unroll
        for (int ct = 0; ct < 4; ++ct) {
            const int row = ct * 16 + l15;
            const int sw = (row & 7) << 3;
            #pragma unroll
            for (int c = 0; c < 4; ++c) {
                short8 kf = *reinterpret_cast<const short8*>(
                    Kc + row * 128 + ((c * 32 + lg * 8) ^ sw));
                sacc[ct] = __builtin_amdgcn_mfma_f32_16x16x32_bf16(qf[c], kf, sacc[ct], 0, 0, 0);
            }
        }
        __builtin_amdgcn_s_setprio(0);
        const bool dm = (kt == qt);
        #pragma unroll
        for (int j = 0; j < 4; ++j) {
            int qrow = qrow0 + lg * 4 + j;
            float s[4], p[4];
            #pragma unroll
            for (int ct = 0; ct < 4; ++ct) {
                s[ct] = sacc[ct][j] * scale;
                if (dm && (qt * 64 + ct * 16 + l15 > qrow)) s[ct] = -1e30f;
            }
            float mt = fmaxf(fmaxf(s[0], s[1]), fmaxf(s[2], s[3]));
            #pragma unroll
            for (int w = 1; w < 16; w <<= 1) mt = fmaxf(mt, __shfl_xor(mt, w));
            float mnew = fmaxf(mrow[j], mt);
            float corr = __expf(mrow[j] - mnew);
            float psum = 0.f;
            #pragma unroll
            for (int ct = 0; ct < 4; ++ct) { p[ct] = __expf(s[ct] - mnew); psum += p[ct]; }
            #pragma unroll
            for (int w = 1; w < 16; w <<= 1) psum += __shfl_xor(psum, w);
            lrow[j] = lrow[j] * corr + psum;
            mrow[j] = mnew;
            #pragma unroll
            for (int d = 0; d < 8; ++d) oacc[d][j] *= corr;
            #pragma unroll
            for (int ct = 0; ct < 4; ++ct)
                Pl[wv][lg * 4 + j][ct * 16 + l15] = f2bf(p[ct]);
        }
        __builtin_amdgcn_s_setprio(1);
        #pragma unroll
        for (int c2 = 0; c2 < 2; ++c2) {
            short8 pfr = *reinterpret_cast<const short8*>(&Pl[wv][l15][c2 * 32 + lg * 8]);
            #pragma unroll
            for (int d = 0; d < 8; ++d) {
                short8 vf = *reinterpret_cast<const short8*>(&Vt[cur][d * 16 + l15][c2 * 32 + lg * 8]);
                oacc[d] = __builtin_amdgcn_mfma_f32_16x16x32_bf16(pfr, vf, oacc[d], 0, 0, 0);
            }
        }
        __builtin_amdgcn_s_setprio(0);
        if (pfn) {
            #pragma unroll
            for (int cc = 0; cc < 4; ++cc) {
                const ushort* e = reinterpret_cast<const ushort*>(&vr[cc]);
                #pragma unroll
                for (int j = 0; j < 8; ++j) Vt[cur ^ 1][wv * 32 + cc * 8 + j][lane] = e[j];
            }
        }
        __syncthreads();
        cur ^= 1;
    }
    const int b = bh >> 4, h = bh & (H_ - 1);
    #pragma unroll
    for (int j = 0; j < 4; ++j) {
        int qrow = qt * 64 + wv * 16 + lg * 4 + j;
        float inv = 1.0f / lrow[j];
        ushort* op = Om + ((size_t)(b * S_ + qrow)) * D_ + h * HD_;
        #pragma unroll
        for (int d = 0; d < 8; ++d)
            op[d * 16 + l15] = f2bf(oacc[d][j] * inv);
    }
}

extern "C" void kernel_launch(void* const* d_in, const int* in_sizes, int n_in,
                              void* d_out, int out_size, void* d_ws, size_t ws_size,
                              hipStream_t stream) {
    const float* x    = (const float*)d_in[0];
    const float* cosT = (const float*)d_in[1];
    const float* sinT = (const float*)d_in[2];
    const float* wq   = (const float*)d_in[3];
    const float* wk   = (const float*)d_in[4];
    const float* wv   = (const float*)d_in[5];
    const float* wo   = (const float*)d_in[6];
    float* out = (float*)d_out;

    char* ws = (char*)d_ws;
    const size_t szX = (size_t)B_ * S_ * D_ * 2;  // 16.78 MB
    const size_t szW = (size_t)D_ * D_ * 2;       // 8.39 MB
    ushort* xb   = (ushort*)(ws);
    ushort* wcat = (ushort*)(ws + szX);                 // [6144][2048] = wqT|wkT|wvT
    ushort* woT  = (ushort*)(ws + szX + 3 * szW);
    ushort* q0   = (ushort*)(ws + szX + 4 * szW);
    ushort* k0   = (ushort*)(ws + szX + 4 * szW + szX);
    ushort* v0   = (ushort*)(ws + szX + 4 * szW + 2 * szX);
    ushort* att  = xb;  // xb dead after QKV GEMM; reuse as attention output

    hipFuncSetAttribute(reinterpret_cast<const void*>(&gemm8<0>),
                        hipFuncAttributeMaxDynamicSharedMemorySize, 131072);
    hipFuncSetAttribute(reinterpret_cast<const void*>(&gemm8<1>),
                        hipFuncAttributeMaxDynamicSharedMemorySize, 131072);

    const int nx = B_ * S_ * D_;
    cast_kernel<<<nx / 4 / 256, 256, 0, stream>>>(x, xb, nx / 4);
    dim3 tg(D_ / 64, D_ / 64);
    cast_transpose_kernel<<<tg, 256, 0, stream>>>(wq, wcat);
    cast_transpose_kernel<<<tg, 256, 0, stream>>>(wk, wcat + (size_t)D_ * D_);
    cast_transpose_kernel<<<tg, 256, 0, stream>>>(wv, wcat + 2 * (size_t)D_ * D_);
    cast_transpose_kernel<<<tg, 256, 0, stream>>>(wo, woT);

    // fused QKV: M=4096, N=6144 -> 384 wgs
    gemm8<0><<<384, 512, 131072, stream>>>(xb, wcat, q0, k0, v0, nullptr, 24);

    const int npairs = B_ * S_ * H_ * 64;
    rope_kernel<<<npairs / 256, 256, 0, stream>>>(q0, cosT, sinT, npairs);
    rope_kernel<<<npairs / 256, 256, 0, stream>>>(v0, cosT, sinT, npairs);  // reference rotates v, not k

    attn3<<<dim3(B_ * H_, S_ / 64), 256, 0, stream>>>(q0, k0, v0, att);

    // out projection: M=4096, N=2048 -> 128 wgs
    gemm8<1><<<128, 512, 131072, stream>>>(att, woT, nullptr, nullptr, nullptr, out, 8);
}

// Round 5
// 277.710 us; speedup vs baseline: 3.9066x; 1.1026x over previous
//
#include <hip/hip_runtime.h>
#include <hip/hip_bf16.h>

typedef short short8 __attribute__((ext_vector_type(8)));
typedef float f32x4 __attribute__((ext_vector_type(4)));
typedef int int4v __attribute__((ext_vector_type(4)));

#define B_ 2
#define S_ 2048
#define D_ 2048
#define H_ 16
#define HD_ 128
#define K_ 2048   // GEMM K (both projections)

#define GLL16(gp, lp) __builtin_amdgcn_global_load_lds( \
    (const __attribute__((address_space(1))) void*)(gp), \
    (__attribute__((address_space(3))) void*)(lp), 16, 0, 0)

__device__ inline ushort f2bf(float f) {
    union { float f; unsigned u; } v; v.f = f;
    unsigned r = v.u + 0x7FFFu + ((v.u >> 16) & 1u);
    return (ushort)(r >> 16);
}
__device__ inline float bf2f(ushort b) {
    union { unsigned u; float f; } v; v.u = ((unsigned)b) << 16;
    return v.f;
}

// fp32 -> bf16 cast, 4 elems/thread
__global__ void cast_kernel(const float* __restrict__ src, ushort* __restrict__ dst, int n4) {
    int i = blockIdx.x * blockDim.x + threadIdx.x;
    if (i >= n4) return;
    float4 v = reinterpret_cast<const float4*>(src)[i];
    ushort4 o;
    o.x = f2bf(v.x); o.y = f2bf(v.y); o.z = f2bf(v.z); o.w = f2bf(v.w);
    reinterpret_cast<ushort4*>(dst)[i] = o;
}

// w[K][N] f32 -> wT[N][K] bf16 via 64x64 LDS tile (one-time)
__global__ __launch_bounds__(256) void cast_transpose_kernel(const float* __restrict__ src,
                                                             ushort* __restrict__ dst) {
    __shared__ ushort tile[64][72];
    const int bk = blockIdx.y * 64, bn = blockIdx.x * 64;
    const int t = threadIdx.x;
    #pragma unroll
    for (int it = 0; it < 4; ++it) {
        int id = t + it * 256;
        int row = id >> 4;
        int c4 = (id & 15) * 4;
        float4 v = *reinterpret_cast<const float4*>(&src[(size_t)(bk + row) * D_ + bn + c4]);
        ushort4 o; o.x = f2bf(v.x); o.y = f2bf(v.y); o.z = f2bf(v.z); o.w = f2bf(v.w);
        *reinterpret_cast<ushort4*>(&tile[row][c4]) = o;
    }
    __syncthreads();
    #pragma unroll
    for (int it = 0; it < 4; ++it) {
        int id = t + it * 256;
        int n = id >> 4;
        int c4 = (id & 15) * 4;
        ushort4 o;
        o.x = tile[c4 + 0][n]; o.y = tile[c4 + 1][n];
        o.z = tile[c4 + 2][n]; o.w = tile[c4 + 3][n];
        *reinterpret_cast<ushort4*>(&dst[(size_t)(bn + n) * D_ + bk + c4]) = o;
    }
}

// in-place RoPE on (B*H, S, HD) bf16, one (even,odd) pair per thread
__global__ void rope_kernel(ushort* __restrict__ t, const float* __restrict__ cosT,
                            const float* __restrict__ sinT, int npairs) {
    int pid = blockIdx.x * blockDim.x + threadIdx.x;
    if (pid >= npairs) return;
    int i = pid & 63;
    int s = (pid >> 6) & (S_ - 1);
    unsigned pr = reinterpret_cast<unsigned*>(t)[pid];
    float e = bf2f((ushort)(pr & 0xFFFFu));
    float o = bf2f((ushort)(pr >> 16));
    float c = cosT[s * 64 + i];
    float sn = sinT[s * 64 + i];
    float oe = e * c - o * sn;
    float oo = e * sn + o * c;
    unsigned outp = ((unsigned)f2bf(oo) << 16) | (unsigned)f2bf(oe);
    reinterpret_cast<unsigned*>(t)[pid] = outp;
}

// ===================== 256xBN 8-phase GEMM (T1+T2+T3+T4+T5) =====================
// MODE 0: BN=256, N=6144 fused QKV -> bf16 (B*H,S,HD).  MODE 1: BN=128, N=2048 -> f32.
#define BAR8() __builtin_amdgcn_s_barrier()
#define VMC0() asm volatile("s_waitcnt vmcnt(0)" ::: "memory")

template<int MODE>
__global__ __launch_bounds__(512, 2) void gemm8(const ushort* __restrict__ A,
        const ushort* __restrict__ Bt, ushort* __restrict__ q0, ushort* __restrict__ k0,
        ushort* __restrict__ v0, float* __restrict__ outf, int nbx) {
    constexpr int NC      = (MODE == 0) ? 4 : 2;       // col frags per wave
    constexpr int BN      = (MODE == 0) ? 256 : 128;
    constexpr int BHROWS  = BN / 2;                    // rows per B half
    constexpr int BHBYTES = BHROWS * 128;              // 16384 / 8192
    constexpr int BSTRIDE = 32768 + 2 * BHBYTES;       // 65536 / 49152
    constexpr int WROWS   = BHROWS / 2;                // 64 / 32

    extern __shared__ char smem[];
    const int tid = threadIdx.x, lane = tid & 63, wv = tid >> 6;
    const int wm = wv >> 2, wn = wv & 3;
    const int l15 = lane & 15, lg = lane >> 4;
    const int nwg = (int)gridDim.x, cpx = nwg >> 3;
    const int swzb = ((int)blockIdx.x & 7) * cpx + ((int)blockIdx.x >> 3);
    const int bn = (swzb % nbx) * BN, bm = (swzb / nbx) * 256;

    f32x4 acc[8][NC] = {};

    const int grl = wv * 8 + (lane >> 3);
    const int swc = (((lane & 7) ^ ((lane >> 3) & 7)) * 8);
    const ushort* Ag = A + (size_t)(bm + grl) * K_ + swc;
    const ushort* Bg = Bt + (size_t)(bn + grl) * K_ + swc;
    const size_t rowHA = (size_t)128 * K_;
    const size_t rowHB = (size_t)BHROWS * K_;
    const size_t row64 = (size_t)64 * K_;

#define VMC() do { if (MODE == 0) asm volatile("s_waitcnt vmcnt(2)" ::: "memory"); \
                   else           asm volatile("s_waitcnt vmcnt(1)" ::: "memory"); } while (0)
#define STAGE_A(t, h) do { if ((t) < 32) { \
        const ushort* g = Ag + (size_t)(h) * rowHA + (size_t)(t) * 64; \
        char* l = smem + (((t) & 1) ? BSTRIDE : 0) + ((h) << 14) + (wv << 10); \
        GLL16(g, l); GLL16(g + row64, l + 8192); } } while (0)
#define STAGE_B(t, h) do { if ((t) < 32) { \
        const ushort* g = Bg + (size_t)(h) * rowHB + (size_t)(t) * 64; \
        char* l = smem + (((t) & 1) ? BSTRIDE : 0) + 32768 + (h) * BHBYTES + (wv << 10); \
        GLL16(g, l); if (MODE == 0) GLL16(g + row64, l + 8192); } } while (0)

    const int colsw0 = (lg * 16) ^ ((l15 & 7) << 4);
    const int colsw1 = (64 + lg * 16) ^ ((l15 & 7) << 4);
    const char* abase0 = smem + (wm << 14);
    const char* bbase0 = smem + 32768 + (wn >> 1) * BHBYTES;
    const char* abase1 = abase0 + BSTRIDE;
    const char* bbase1 = bbase0 + BSTRIDE;
    const int brow = ((wn & 1) * WROWS + l15) * 128;

#define LDA(ab, q, cs) do { _Pragma("unroll") for (int f = 0; f < 4; ++f) \
        a[f] = *reinterpret_cast<const short8*>((ab) + ((q) * 64 + f * 16 + l15) * 128 + (cs)); } while (0)
#define LDB(bb, cs) do { _Pragma("unroll") for (int c = 0; c < NC; ++c) \
        b[c] = *reinterpret_cast<const short8*>((bb) + brow + c * 2048 + (cs)); } while (0)
#define MM(q) do { __builtin_amdgcn_s_setprio(1); \
        _Pragma("unroll") for (int f = 0; f < 4; ++f) \
        _Pragma("unroll") for (int c = 0; c < NC; ++c) \
            acc[(q) * 4 + f][c] = __builtin_amdgcn_mfma_f32_16x16x32_bf16(a[f], b[c], acc[(q) * 4 + f][c], 0, 0, 0); \
        __builtin_amdgcn_s_setprio(0); } while (0)

    STAGE_A(0, 0); STAGE_A(0, 1); STAGE_B(0, 0); STAGE_B(0, 1);
    STAGE_B(1, 0);
    VMC();
    BAR8();

    for (int i = 0; i < 16; ++i) {
        const int t1 = 2 * i + 1, s0 = 2 * i + 2, s1 = 2 * i + 3;
        short8 a[4], b[NC];
        // ph1: tile 2i (buf0)
        LDB(bbase0, colsw0); LDA(abase0, 0, colsw0);
        STAGE_A(t1, 0);
        BAR8(); MM(0); BAR8();
        // ph2
        LDA(abase0, 1, colsw0);
        STAGE_A(t1, 1);
        BAR8(); MM(1); BAR8();
        // ph3
        LDB(bbase0, colsw1); LDA(abase0, 0, colsw1);
        STAGE_B(t1, 1);
        BAR8(); MM(0); BAR8();
        // ph4: ensure tile 2i+1 resident before ph5
        LDA(abase0, 1, colsw1);
        STAGE_B(s0, 0);
        if (s0 < 32) VMC(); else VMC0();
        BAR8(); MM(1); BAR8();
        // ph5: tile 2i+1 (buf1)
        LDB(bbase1, colsw0); LDA(abase1, 0, colsw0);
        STAGE_A(s0, 0);
        BAR8(); MM(0); BAR8();
        // ph6
        LDA(abase1, 1, colsw0);
        STAGE_A(s0, 1);
        BAR8(); MM(1); BAR8();
        // ph7
        LDB(bbase1, colsw1); LDA(abase1, 0, colsw1);
        STAGE_B(s0, 1);
        BAR8(); MM(0); BAR8();
        // ph8: ensure tile 2i+2 resident before next ph1
        LDA(abase1, 1, colsw1);
        STAGE_B(s1, 0);
        if (s1 < 32) VMC(); else VMC0();
        BAR8(); MM(1); BAR8();
    }

    const int colbase = bn + wn * (BN / 4);
    if (MODE == 0) {
        const int seg = colbase >> 11;
        ushort* segp = (seg == 0) ? q0 : ((seg == 1) ? k0 : v0);
        #pragma unroll
        for (int rf = 0; rf < 8; ++rf)
            #pragma unroll
            for (int c = 0; c < NC; ++c)
                #pragma unroll
                for (int j = 0; j < 4; ++j) {
                    int row = bm + wm * 128 + rf * 16 + lg * 4 + j;
                    int col = colbase + c * 16 + l15;
                    int bb = row >> 11, s = row & (S_ - 1);
                    int h = (col >> 7) & (H_ - 1), d = col & (HD_ - 1);
                    segp[(((size_t)(bb * H_ + h)) * S_ + s) * HD_ + d] = f2bf(acc[rf][c][j]);
                }
    } else {
        #pragma unroll
        for (int rf = 0; rf < 8; ++rf)
            #pragma unroll
            for (int c = 0; c < NC; ++c)
                #pragma unroll
                for (int j = 0; j < 4; ++j) {
                    int row = bm + wm * 128 + rf * 16 + lg * 4 + j;
                    int col = colbase + c * 16 + l15;
                    outf[(size_t)row * D_ + col] = acc[rf][c][j];
                }
    }
#undef VMC
#undef STAGE_A
#undef STAGE_B
#undef LDA
#undef LDB
#undef MM
}

// ============ causal flash attention v4: swapped QK^T, in-lane softmax ============
// 4 waves, 64 q-rows/block. Scores S^T[key][q]: lane(lg,l15) reg(ct,j) holds
// key=ct*16+lg*4+j for q-row l15 -> softmax is in-lane + 4 shuffles/tile.
// PV computes O^T = mfma(V^T, P^T): rescale corr lane-local. Defer-max (T13).
// P^T redistribution: cvt_pk pairs + 16 bpermute + 8 selects (no P LDS).
__global__ __launch_bounds__(256) void attn4(const ushort* __restrict__ Qm,
        const ushort* __restrict__ Km, const ushort* __restrict__ Vm,
        ushort* __restrict__ Om) {
    __shared__ __align__(16) ushort Kb[2][64 * 128];   // swizzled [key][d]
    __shared__ __align__(16) ushort Vt[2][128][72];    // [d][key]
    const int tid = threadIdx.x, lane = tid & 63, wv = tid >> 6;
    const int l15 = lane & 15, lg = lane >> 4;
    const int qt = 31 - (int)blockIdx.y;   // heavy tiles first
    const int bh = blockIdx.x;
    const size_t base = (size_t)bh * S_ * HD_;
    const int qrow0 = qt * 64 + wv * 16;
    const float C = 0.1275174f;            // (1/sqrt(128)) * log2(e)

    short8 qf[4];
    {
        const ushort* qp = Qm + base + (size_t)(qrow0 + l15) * HD_;
        #pragma unroll
        for (int c = 0; c < 4; ++c)
            qf[c] = *reinterpret_cast<const short8*>(qp + c * 32 + lg * 8);
    }
    f32x4 oacc[8] = {};   // O^T: oacc[dt][j] = O[q=l15][d=dt*16+lg*4+j]
    float mS = -1e30f, lS = 0.f;
    const int ntiles = qt + 1;
    const int qv = wv * 16 + l15;   // q position within the 64-row block

    // prologue: stage tile 0
    {
        #pragma unroll
        for (int c = 0; c < 4; ++c) {
            int row = wv * 16 + c * 4 + (lane >> 4);
            GLL16(Km + base + (size_t)row * HD_ + (((lane & 15) ^ (row & 7)) << 3),
                  &Kb[0][wv * 2048 + c * 512]);
        }
        const ushort* vp = Vm + base + (size_t)lane * HD_ + wv * 32;
        #pragma unroll
        for (int cc = 0; cc < 4; ++cc) {
            int4v v = *reinterpret_cast<const int4v*>(vp + cc * 8);
            const ushort* e = reinterpret_cast<const ushort*>(&v);
            #pragma unroll
            for (int j = 0; j < 8; ++j) Vt[0][wv * 32 + cc * 8 + j][lane] = e[j];
        }
    }
    __syncthreads();

    int cur = 0;
    for (int kt = 0; kt < ntiles; ++kt) {
        const bool pfn = (kt + 1 < ntiles);
        int4v vr[4];
        if (pfn) {   // issue next-tile prefetch first: hides under this tile's compute
            const int r0 = (kt + 1) * 64;
            #pragma unroll
            for (int c = 0; c < 4; ++c) {
                int row = wv * 16 + c * 4 + (lane >> 4);
                GLL16(Km + base + (size_t)(r0 + row) * HD_ + (((lane & 15) ^ (row & 7)) << 3),
                      &Kb[cur ^ 1][wv * 2048 + c * 512]);
            }
            const ushort* vp = Vm + base + (size_t)(r0 + lane) * HD_ + wv * 32;
            #pragma unroll
            for (int cc = 0; cc < 4; ++cc)
                vr[cc] = *reinterpret_cast<const int4v*>(vp + cc * 8);
        }
        // S^T = K @ Q^T from swizzled LDS (operands swapped vs classic)
        f32x4 sacc[4] = {};
        const ushort* Kc = &Kb[cur][0];
        __builtin_amdgcn_s_setprio(1);
        #pragma unroll
        for (int ct = 0; ct < 4; ++ct) {
            const int row = ct * 16 + l15;
            const int sw = (row & 7) << 3;
            #pragma unroll
            for (int c = 0; c < 4; ++c) {
                short8 kf = *reinterpret_cast<const short8*>(
                    Kc + row * 128 + ((c * 32 + lg * 8) ^ sw));
                sacc[ct] = __builtin_amdgcn_mfma_f32_16x16x32_bf16(kf, qf[c], sacc[ct], 0, 0, 0);
            }
        }
        __builtin_amdgcn_s_setprio(0);

        // in-lane online softmax over 16 regs (keys ct*16+lg*4+j), q = l15
        float t16[16];
        #pragma unroll
        for (int ct = 0; ct < 4; ++ct)
            #pragma unroll
            for (int j = 0; j < 4; ++j) t16[ct * 4 + j] = sacc[ct][j];
        if (kt == qt) {   // diagonal tile: mask key > q
            #pragma unroll
            for (int ct = 0; ct < 4; ++ct)
                #pragma unroll
                for (int j = 0; j < 4; ++j)
                    if (ct * 16 + lg * 4 + j > qv) t16[ct * 4 + j] = -1e30f;
        }
        float mx[8];
        #pragma unroll
        for (int i = 0; i < 8; ++i) mx[i] = fmaxf(t16[i], t16[i + 8]);
        #pragma unroll
        for (int i = 0; i < 4; ++i) mx[i] = fmaxf(mx[i], mx[i + 4]);
        float m64 = fmaxf(fmaxf(mx[0], mx[1]), fmaxf(mx[2], mx[3]));
        m64 = fmaxf(m64, __shfl_xor(m64, 16));
        m64 = fmaxf(m64, __shfl_xor(m64, 32));
        // defer-max: only rescale when some row's max grew past threshold
        if (!__all(m64 - mS <= 47.0f)) {
            float mnew = fmaxf(mS, m64);
            float corr = __builtin_amdgcn_exp2f((mS - mnew) * C);
            lS *= corr;
            #pragma unroll
            for (int dt = 0; dt < 8; ++dt)
                #pragma unroll
                for (int j = 0; j < 4; ++j) oacc[dt][j] *= corr;
            mS = mnew;
        }
        const float mcc = mS * C;
        float p[16];
        #pragma unroll
        for (int i = 0; i < 16; ++i)
            p[i] = __builtin_amdgcn_exp2f(fmaf(t16[i], C, -mcc));
        float sm[8];
        #pragma unroll
        for (int i = 0; i < 8; ++i) sm[i] = p[i] + p[i + 8];
        #pragma unroll
        for (int i = 0; i < 4; ++i) sm[i] = sm[i] + sm[i + 4];
        float psum = (sm[0] + sm[1]) + (sm[2] + sm[3]);
        psum += __shfl_xor(psum, 16);
        psum += __shfl_xor(psum, 32);
        lS += psum;

        // pack P pairs to bf16 dwords: dw[ct*2+u] = keys ct*16+lg*4+{2u,2u+1}
        unsigned dw[8];
        #pragma unroll
        for (int ct = 0; ct < 4; ++ct)
            #pragma unroll
            for (int u = 0; u < 2; ++u) {
                __hip_bfloat162 h2 = __float22bfloat162_rn(
                    float2{p[ct * 4 + 2 * u], p[ct * 4 + 2 * u + 1]});
                dw[ct * 2 + u] = *reinterpret_cast<unsigned*>(&h2);
            }
        // O^T += V^T @ P^T
        #pragma unroll
        for (int c2 = 0; c2 < 2; ++c2) {
            int4v pfd;
            #pragma unroll
            for (int d = 0; d < 4; ++d) {
                int srcl = (lg & 1) * 32 + (d >> 1) * 16 + l15;
                int r0 = __shfl((int)dw[(2 * c2) * 2 + (d & 1)], srcl);
                int r1 = __shfl((int)dw[(2 * c2 + 1) * 2 + (d & 1)], srcl);
                pfd[d] = (lg & 2) ? r1 : r0;
            }
            short8 pf = *reinterpret_cast<short8*>(&pfd);
            __builtin_amdgcn_s_setprio(1);
            #pragma unroll
            for (int dt = 0; dt < 8; ++dt) {
                short8 vf = *reinterpret_cast<const short8*>(
                    &Vt[cur][dt * 16 + l15][c2 * 32 + lg * 8]);
                oacc[dt] = __builtin_amdgcn_mfma_f32_16x16x32_bf16(vf, pf, oacc[dt], 0, 0, 0);
            }
            __builtin_amdgcn_s_setprio(0);
        }
        // late write of prefetched V into the other buffer
        if (pfn) {
            #pragma unroll
            for (int cc = 0; cc < 4; ++cc) {
                const ushort* e = reinterpret_cast<const ushort*>(&vr[cc]);
                #pragma unroll
                for (int j = 0; j < 8; ++j) Vt[cur ^ 1][wv * 32 + cc * 8 + j][lane] = e[j];
            }
        }
        __syncthreads();
        cur ^= 1;
    }
    const int b = bh >> 4, h = bh & (H_ - 1);
    const int q = qt * 64 + wv * 16 + l15;
    const float inv = 1.0f / lS;
    ushort* op = Om + ((size_t)(b * S_ + q)) * D_ + h * HD_;
    #pragma unroll
    for (int dt = 0; dt < 8; ++dt) {
        ushort4 o;
        o.x = f2bf(oacc[dt][0] * inv);
        o.y = f2bf(oacc[dt][1] * inv);
        o.z = f2bf(oacc[dt][2] * inv);
        o.w = f2bf(oacc[dt][3] * inv);
        *reinterpret_cast<ushort4*>(op + dt * 16 + lg * 4) = o;
    }
}

extern "C" void kernel_launch(void* const* d_in, const int* in_sizes, int n_in,
                              void* d_out, int out_size, void* d_ws, size_t ws_size,
                              hipStream_t stream) {
    const float* x    = (const float*)d_in[0];
    const float* cosT = (const float*)d_in[1];
    const float* sinT = (const float*)d_in[2];
    const float* wq   = (const float*)d_in[3];
    const float* wk   = (const float*)d_in[4];
    const float* wv   = (const float*)d_in[5];
    const float* wo   = (const float*)d_in[6];
    float* out = (float*)d_out;

    char* ws = (char*)d_ws;
    const size_t szX = (size_t)B_ * S_ * D_ * 2;  // 16.78 MB
    const size_t szW = (size_t)D_ * D_ * 2;       // 8.39 MB
    ushort* xb   = (ushort*)(ws);
    ushort* wcat = (ushort*)(ws + szX);                 // [6144][2048] = wqT|wkT|wvT
    ushort* woT  = (ushort*)(ws + szX + 3 * szW);
    ushort* q0   = (ushort*)(ws + szX + 4 * szW);
    ushort* k0   = (ushort*)(ws + szX + 4 * szW + szX);
    ushort* v0   = (ushort*)(ws + szX + 4 * szW + 2 * szX);
    ushort* att  = xb;  // xb dead after QKV GEMM; reuse as attention output

    hipFuncSetAttribute(reinterpret_cast<const void*>(&gemm8<0>),
                        hipFuncAttributeMaxDynamicSharedMemorySize, 131072);
    hipFuncSetAttribute(reinterpret_cast<const void*>(&gemm8<1>),
                        hipFuncAttributeMaxDynamicSharedMemorySize, 98304);

    const int nx = B_ * S_ * D_;
    cast_kernel<<<nx / 4 / 256, 256, 0, stream>>>(x, xb, nx / 4);
    dim3 tg(D_ / 64, D_ / 64);
    cast_transpose_kernel<<<tg, 256, 0, stream>>>(wq, wcat);
    cast_transpose_kernel<<<tg, 256, 0, stream>>>(wk, wcat + (size_t)D_ * D_);
    cast_transpose_kernel<<<tg, 256, 0, stream>>>(wv, wcat + 2 * (size_t)D_ * D_);
    cast_transpose_kernel<<<tg, 256, 0, stream>>>(wo, woT);

    // fused QKV: M=4096, N=6144, BN=256 -> 384 wgs
    gemm8<0><<<384, 512, 131072, stream>>>(xb, wcat, q0, k0, v0, nullptr, 24);

    const int npairs = B_ * S_ * H_ * 64;
    rope_kernel<<<npairs / 256, 256, 0, stream>>>(q0, cosT, sinT, npairs);
    rope_kernel<<<npairs / 256, 256, 0, stream>>>(v0, cosT, sinT, npairs);  // reference rotates v, not k

    attn4<<<dim3(B_ * H_, S_ / 64), 256, 0, stream>>>(q0, k0, v0, att);

    // out projection: M=4096, N=2048, BN=128 -> 256 wgs (one full round)
    gemm8<1><<<256, 512, 98304, stream>>>(att, woT, nullptr, nullptr, nullptr, out, 16);
}